// Round 6
// baseline (135.851 us; speedup 1.0000x reference)
//
#include <hip/hip_runtime.h>
#include <math.h>

#define DDIM 4096
#define NEXP 64

typedef short s16x8 __attribute__((ext_vector_type(8)));
typedef float f32x4 __attribute__((ext_vector_type(4)));

__device__ __forceinline__ unsigned cvt_pk_bf16(float a, float b) {
  unsigned r;
  asm("v_cvt_pk_bf16_f32 %0, %1, %2" : "=v"(r) : "v"(a), "v"(b));
  return r;  // lo16 = bf16(a), hi16 = bf16(b)
}

// 3-way bf16 split of two floats -> packed hi/mid/lo words
__device__ __forceinline__ void split2(float a, float b, unsigned& H,
                                       unsigned& M, unsigned& L) {
  H = cvt_pk_bf16(a, b);
  float h0 = __uint_as_float(H << 16);
  float h1 = __uint_as_float(H & 0xffff0000u);
  float r0 = a - h0, r1 = b - h1;
  M = cvt_pk_bf16(r0, r1);
  float m0 = __uint_as_float(M << 16);
  float m1 = __uint_as_float(M & 0xffff0000u);
  L = cvt_pk_bf16(r0 - m0, r1 - m1);
}

union U8 { unsigned u[4]; s16x8 v; };
__device__ __forceinline__ s16x8 pack8(const unsigned* a) {
  U8 t;
  t.u[0] = a[0]; t.u[1] = a[1]; t.u[2] = a[2]; t.u[3] = a[3];
  return t.v;
}

// stage 4 tokens' contiguous 1KB k-windows into LDS (one row-burst each).
// LDS slot l of token t holds global 16B chunk (l ^ (t&7)) -> source
// pre-swizzle so swizzled ds_reads are conflict-free (rule #21).
__device__ __forceinline__ void stage_x(const float* __restrict__ x, char* dst,
                                        int tok0, int tg, int eg, int win,
                                        int lane) {
#pragma unroll
  for (int j = 0; j < 4; ++j) {
    const int t = (tg << 4) + (eg << 2) + j;  // block-local token
    const float* src =
        x + (size_t)(tok0 + t) * DDIM + (win << 8) + ((lane ^ (t & 7)) << 2);
    __builtin_amdgcn_global_load_lds(
        (const __attribute__((address_space(1))) void*)src,
        (__attribute__((address_space(3))) void*)(dst + t * 1024), 16, 0, 0);
  }
}

#define MFMA(A, B, C) __builtin_amdgcn_mfma_f32_16x16x32_bf16(A, B, C, 0, 0, 0)

// 16 waves, 64 tokens/block. wave = (token-group tg, expert-group eg):
// one 16x16 output tile per wave, k swept jointly by all waves.
// x: LDS-staged in 1KB/token contiguous bursts (HBM row locality).
// w: fragment blob read global->VGPR (L2-resident, L1 reuse x4).
__global__ __launch_bounds__(1024, 1) void moe_gate_main(
    const float* __restrict__ x,    // [N][4096]
    const ushort* __restrict__ wf,  // [128kb][4eg][3lvl][64lane][8] bf16 bits
    float* __restrict__ out,        // idx [N*8], w [N*8], aux
    float* __restrict__ pi_g, float* __restrict__ ce_g, int N) {
  __shared__ float smem[32768];  // 128 KB: x dbuf 2x64KB; epilogue reuses
  float* lt = smem;              // logits [64 e][stride 68]
  float* inv_s = smem + 4352;
  float* ce_lds = smem + 4416;
  char* xbase = (char*)smem;

  const int tid = threadIdx.x;
  const int lane = tid & 63;
  const int wv = tid >> 6;   // 0..15
  const int tg = wv >> 2;    // token group (16 tokens)
  const int eg = wv & 3;     // expert group (16 experts)
  const int tok0 = blockIdx.x << 6;
  const int rot = (blockIdx.x * 7) & 15;  // k-window rotation (order-invariant)

  const int tl = (tg << 4) + (lane & 15);  // this lane's token (read side)
  const int swz = tl & 7;
  const char* xrow = xbase + tl * 1024;

  f32x4 accH = {0.f, 0.f, 0.f, 0.f}, accC = {0.f, 0.f, 0.f, 0.f};

  stage_x(x, xbase, tok0, tg, eg, rot, lane);
  __syncthreads();

#pragma unroll 1
  for (int sl = 0; sl < 16; ++sl) {
    const int win = (sl + rot) & 15;
    if (sl + 1 < 16)
      stage_x(x, xbase + ((sl + 1) & 1) * 65536, tok0, tg, eg,
              (sl + 1 + rot) & 15, lane);
    const char* xb = xrow + (sl & 1) * 65536;
    const int kb0 = win << 3;
#pragma unroll
    for (int kk = 0; kk < 8; ++kk) {
      const int c0 = (kk << 3) + ((lane >> 4) << 1);
      const f32x4 xa = *(const f32x4*)(xb + ((c0 ^ swz) << 4));
      const f32x4 xv = *(const f32x4*)(xb + (((c0 + 1) ^ swz) << 4));
      unsigned AH[4], AM[4], AL[4];
      split2(xa[0], xa[1], AH[0], AM[0], AL[0]);
      split2(xa[2], xa[3], AH[1], AM[1], AL[1]);
      split2(xv[0], xv[1], AH[2], AM[2], AL[2]);
      split2(xv[2], xv[3], AH[3], AM[3], AL[3]);
      const s16x8 ah = pack8(AH), am = pack8(AM), al = pack8(AL);
      const ushort* wfe =
          wf + ((size_t)(kb0 + kk) * 12 + eg * 3) * 512 + lane * 8;
      const s16x8 bh = *(const s16x8*)(wfe);
      const s16x8 bm = *(const s16x8*)(wfe + 512);
      const s16x8 bl = *(const s16x8*)(wfe + 1024);
      accH = MFMA(ah, bh, accH);
      accC = MFMA(ah, bm, accC);
      accC = MFMA(am, bh, accC);
      accC = MFMA(am, bm, accC);
      accC = MFMA(ah, bl, accC);
      accC = MFMA(al, bh, accC);
    }
    __syncthreads();
  }

  // logits -> lt[expert*68 + token], unscale by 1/64 (w pre-scaled x64)
#pragma unroll
  for (int r = 0; r < 4; ++r) {
    lt[(eg * 16 + (lane & 15)) * 68 + tg * 16 + ((lane >> 4) << 2) + r] =
        (accH[r] + accC[r]) * 0.015625f;
  }
  __syncthreads();

  // softmax per token (store p = exp(l-m) back)
  if (tid < 64) {
    const int t = tid;
    ce_lds[t] = 0.f;
    float m = -1e30f;
#pragma unroll 1
    for (int e = 0; e < 64; ++e) m = fmaxf(m, lt[e * 68 + t]);
    float ssum = 0.f;
#pragma unroll 1
    for (int e = 0; e < 64; ++e) {
      float p = expf(lt[e * 68 + t] - m);
      lt[e * 68 + t] = p;
      ssum += p;
    }
    inv_s[t] = 1.f / ssum;
  }
  __syncthreads();

  // pi partial: per-expert sum of scores
  if (tid < 64) {
    const int e = tid;
    float ssum = 0.f;
#pragma unroll 1
    for (int t = 0; t < 64; ++t) ssum += lt[e * 68 + t] * inv_s[t];
    atomicAdd(pi_g + e, ssum);
  }
  __syncthreads();

  // stable top-8 (strict > keeps lowest index on ties; descending)
  if (tid < 64) {
    const int t = tid;
    const float invv = inv_s[t];
    const size_t tg2 = (size_t)(tok0 + t);
#pragma unroll 1
    for (int r = 0; r < 8; ++r) {
      float bv = -1.f;
      int bi = 0;
#pragma unroll 1
      for (int e = 0; e < 64; ++e) {
        float p = lt[e * 68 + t];
        if (p > bv) { bv = p; bi = e; }
      }
      lt[bi * 68 + t] = -1.f;
      atomicAdd(ce_lds + bi, 1.f);
      out[tg2 * 8 + r] = (float)bi;
      out[(size_t)N * 8 + tg2 * 8 + r] = bv * invv;
    }
  }
  __syncthreads();
  if (tid < 64) atomicAdd(ce_g + tid, ce_lds[tid]);
}

// w [64][4096] -> fragment-ordered 3-way split blob, scaled by 64
__global__ void build_wfrag(const float* __restrict__ w, ushort* __restrict__ wf) {
  const int kb = blockIdx.x;  // 0..127
  const int t = threadIdx.x;  // 256
  const int eg = t >> 6, lane = t & 63;
  const int e = (eg << 4) + (lane & 15);
  const int k0 = (kb << 5) + ((lane >> 4) << 3);
  const float* src = w + (size_t)e * DDIM + k0;
  unsigned H[4], M[4], L[4];
#pragma unroll
  for (int i = 0; i < 4; ++i) {
    float a = src[2 * i] * 64.f, b = src[2 * i + 1] * 64.f;
    split2(a, b, H[i], M[i], L[i]);
  }
  const size_t base = ((size_t)kb * 12 + eg * 3) * 512 + (size_t)lane * 8;
  *(uint4*)(wf + base) = make_uint4(H[0], H[1], H[2], H[3]);
  *(uint4*)(wf + base + 512) = make_uint4(M[0], M[1], M[2], M[3]);
  *(uint4*)(wf + base + 1024) = make_uint4(L[0], L[1], L[2], L[3]);
}

__global__ void aux_final(const float* __restrict__ pi_g,
                          const float* __restrict__ ce_g,
                          float* __restrict__ out_aux, int N) {
  const int e = threadIdx.x;  // 64
  float v = (pi_g[e] / (float)N) * (ce_g[e] / ((float)N * 8.0f)) * 64.0f * 0.01f;
#pragma unroll
  for (int off = 32; off; off >>= 1) v += __shfl_down(v, off, 64);
  if (e == 0) *out_aux = v;
}

extern "C" void kernel_launch(void* const* d_in, const int* in_sizes, int n_in,
                              void* d_out, int out_size, void* d_ws, size_t ws_size,
                              hipStream_t stream) {
  (void)n_in; (void)out_size; (void)ws_size;
  const float* x = (const float*)d_in[0];
  const float* w = (const float*)d_in[1];
  float* out = (float*)d_out;
  const int N = in_sizes[0] / DDIM;  // 16384

  ushort* wf = (ushort*)d_ws;  // 128*12*512 ushorts = 1.5 MiB
  float* pi_g = (float*)((char*)d_ws + (size_t)128 * 12 * 512 * 2);
  float* ce_g = pi_g + 64;

  hipMemsetAsync(pi_g, 0, 128 * sizeof(float), stream);
  build_wfrag<<<128, 256, 0, stream>>>(w, wf);
  moe_gate_main<<<N / 64, 1024, 0, stream>>>(x, wf, out, pi_g, ce_g, N);
  aux_final<<<1, 64, 0, stream>>>(pi_g, ce_g, out + (size_t)N * 16, N);
}